// Round 2
// baseline (1758.140 us; speedup 1.0000x reference)
//
#include <hip/hip_runtime.h>
#include <math.h>

#define B_ 4
#define T_ 4096
#define H_ 16
#define D_ 64
#define C_ 1024
#define BT_ (B_*T_)
#define W3 (3*C_)

__device__ __forceinline__ float feature_map(float x) {
    // elu(x) + 1 : x>0 -> x+1 ; else exp(x)
    return x > 0.0f ? x + 1.0f : __expf(x);
}

// ---------------------------------------------------------------------------
// K1: fused k/v GEMM + kv accumulation.
// block = (head h, 128-row tile). GEMM [128x1024]x[1024x128] where the 128
// cols = 64 k-cols ++ 64 v-cols of head h. k_m = elu(k/scale)+1 and v stay in
// LDS; per-block partial kv = k_m^T v (two 64-row passes) -> atomicAdd.
// LDS: phase1 As[16][132]+Bs[16][128] unioned with phase2 kS/vS[64][68].
// ---------------------------------------------------------------------------
__global__ __launch_bounds__(256)
void kv_fused_kernel(const float* __restrict__ x, const float* __restrict__ Wqkv,
                     const float* __restrict__ bqkv, float* __restrict__ kv)
{
    __shared__ float smem[8704];                      // 34.8 KB
    float (*As)[132] = (float (*)[132])smem;          // 16x132
    float (*Bs)[128] = (float (*)[128])(smem + 2112); // 16x128
    float (*kS)[68]  = (float (*)[68])smem;           // 64x68
    float (*vS)[68]  = (float (*)[68])(smem + 4352);  // 64x68

    const int tid = threadIdx.x;
    const int tx = tid & 15;          // 0..15 -> col quad
    const int ty = tid >> 4;          // 0..15 -> row quad
    const int h = blockIdx.x;
    const int mBase = blockIdx.y * 128;
    const int bb = mBase >> 12;       // batch (T=4096, 128 | 4096)

    float acc[8][8];
    #pragma unroll
    for (int i = 0; i < 8; i++)
        #pragma unroll
        for (int j = 0; j < 8; j++) acc[i][j] = 0.0f;

    for (int k0 = 0; k0 < C_; k0 += 16) {
        #pragma unroll
        for (int l = 0; l < 2; l++) {                 // A tile, transposed
            int gid = tid + l * 256;
            int row = gid >> 2, c4 = gid & 3;
            const float4 a4 = *reinterpret_cast<const float4*>(
                &x[(size_t)(mBase + row) * C_ + k0 + c4 * 4]);
            As[c4 * 4 + 0][row] = a4.x;
            As[c4 * 4 + 1][row] = a4.y;
            As[c4 * 4 + 2][row] = a4.z;
            As[c4 * 4 + 3][row] = a4.w;
        }
        #pragma unroll
        for (int l = 0; l < 2; l++) {                 // B tile: k cols ++ v cols
            int gid = tid + l * 256;
            int row = gid >> 5, c4 = gid & 31;
            int lcol = c4 * 4;
            int gcol = (lcol < 64) ? (C_ + h * 64 + lcol)
                                   : (2 * C_ + h * 64 + (lcol - 64));
            *reinterpret_cast<float4*>(&Bs[row][lcol]) =
                *reinterpret_cast<const float4*>(&Wqkv[(size_t)(k0 + row) * W3 + gcol]);
        }
        __syncthreads();

        #pragma unroll
        for (int kk = 0; kk < 16; kk++) {
            float a[8], w[8];
            *reinterpret_cast<float4*>(&a[0]) = *reinterpret_cast<float4*>(&As[kk][ty * 4]);
            *reinterpret_cast<float4*>(&a[4]) = *reinterpret_cast<float4*>(&As[kk][64 + ty * 4]);
            *reinterpret_cast<float4*>(&w[0]) = *reinterpret_cast<float4*>(&Bs[kk][tx * 4]);
            *reinterpret_cast<float4*>(&w[4]) = *reinterpret_cast<float4*>(&Bs[kk][64 + tx * 4]);
            #pragma unroll
            for (int i = 0; i < 8; i++)
                #pragma unroll
                for (int j = 0; j < 8; j++)
                    acc[i][j] = fmaf(a[i], w[j], acc[i][j]);
        }
        __syncthreads();
    }

    const float inv_scale = 0.35355339059327373f;     // 1 / 64^0.25
    float kb[4], vb[4];
    #pragma unroll
    for (int j = 0; j < 4; j++) {
        kb[j] = bqkv[C_ + h * 64 + tx * 4 + j];
        vb[j] = bqkv[2 * C_ + h * 64 + tx * 4 + j];
    }

    float acc2[4][4] = {};
    #pragma unroll
    for (int pass = 0; pass < 2; pass++) {
        __syncthreads();                               // prior readers done
        #pragma unroll
        for (int i = 0; i < 4; i++) {
            const int ii = pass * 4 + i;
            float kv4[4], vv4[4];
            #pragma unroll
            for (int j = 0; j < 4; j++) {
                kv4[j] = feature_map((acc[ii][j] + kb[j]) * inv_scale);
                vv4[j] = acc[ii][4 + j] + vb[j];
            }
            *reinterpret_cast<float4*>(&kS[ty * 4 + i][tx * 4]) =
                make_float4(kv4[0], kv4[1], kv4[2], kv4[3]);
            *reinterpret_cast<float4*>(&vS[ty * 4 + i][tx * 4]) =
                make_float4(vv4[0], vv4[1], vv4[2], vv4[3]);
        }
        __syncthreads();
        #pragma unroll
        for (int r = 0; r < 64; r++) {
            float k4[4], v4[4];
            *reinterpret_cast<float4*>(k4) = *reinterpret_cast<float4*>(&kS[r][ty * 4]);
            *reinterpret_cast<float4*>(v4) = *reinterpret_cast<float4*>(&vS[r][tx * 4]);
            #pragma unroll
            for (int i = 0; i < 4; i++)
                #pragma unroll
                for (int j = 0; j < 4; j++)
                    acc2[i][j] = fmaf(k4[i], v4[j], acc2[i][j]);
        }
    }

    float* kvb = kv + (size_t)(bb * H_ + h) * (D_ * D_);
    #pragma unroll
    for (int i = 0; i < 4; i++)
        #pragma unroll
        for (int j = 0; j < 4; j++)
            atomicAdd(&kvb[(ty * 4 + i) * D_ + tx * 4 + j], acc2[i][j]);
}

// ---------------------------------------------------------------------------
// K2: fused q GEMM + attention apply.
// block = (head h, 128-row tile). GEMM [128x1024]x[1024x64] -> q_m in LDS;
// attn[rows, h*64+m] = (q_m . kv[b,h]) / (sum_d q_m + 1e-6).
// ---------------------------------------------------------------------------
__global__ __launch_bounds__(256)
void qattn_kernel(const float* __restrict__ x, const float* __restrict__ Wqkv,
                  const float* __restrict__ bqkv, const float* __restrict__ kv,
                  float* __restrict__ attn)
{
    __shared__ float smem[8704];                      // 34.8 KB
    float (*As)[132] = (float (*)[132])smem;          // 16x132 (2112)
    float (*Bs)[68]  = (float (*)[68])(smem + 2112);  // 16x68  (1088, ends 3200)
    float (*qS)[68]  = (float (*)[68])smem;           // 64x68  (4352)
    float (*kvS)[68] = (float (*)[68])(smem + 4352);  // 64x68

    const int tid = threadIdx.x;
    const int tx = tid & 15;
    const int ty = tid >> 4;
    const int h = blockIdx.x;
    const int mBase = blockIdx.y * 128;
    const int bb = mBase >> 12;
    const size_t kvbase = (size_t)(bb * H_ + h) * (D_ * D_);

    // load kv slab (64x64) once; consumed after K-loop (syncs inside cover it)
    #pragma unroll
    for (int l = 0; l < 4; l++) {
        int gid = tid + l * 256;
        int d = gid >> 4, m4 = gid & 15;
        *reinterpret_cast<float4*>(&kvS[d][m4 * 4]) =
            *reinterpret_cast<const float4*>(&kv[kvbase + d * 64 + m4 * 4]);
    }

    float acc[8][4];
    #pragma unroll
    for (int i = 0; i < 8; i++)
        #pragma unroll
        for (int j = 0; j < 4; j++) acc[i][j] = 0.0f;

    for (int k0 = 0; k0 < C_; k0 += 16) {
        #pragma unroll
        for (int l = 0; l < 2; l++) {
            int gid = tid + l * 256;
            int row = gid >> 2, c4 = gid & 3;
            const float4 a4 = *reinterpret_cast<const float4*>(
                &x[(size_t)(mBase + row) * C_ + k0 + c4 * 4]);
            As[c4 * 4 + 0][row] = a4.x;
            As[c4 * 4 + 1][row] = a4.y;
            As[c4 * 4 + 2][row] = a4.z;
            As[c4 * 4 + 3][row] = a4.w;
        }
        {
            int row = tid >> 4, c4 = tid & 15;
            *reinterpret_cast<float4*>(&Bs[row][c4 * 4]) =
                *reinterpret_cast<const float4*>(
                    &Wqkv[(size_t)(k0 + row) * W3 + h * 64 + c4 * 4]);
        }
        __syncthreads();

        #pragma unroll
        for (int kk = 0; kk < 16; kk++) {
            float a[8], w[4];
            *reinterpret_cast<float4*>(&a[0]) = *reinterpret_cast<float4*>(&As[kk][ty * 4]);
            *reinterpret_cast<float4*>(&a[4]) = *reinterpret_cast<float4*>(&As[kk][64 + ty * 4]);
            *reinterpret_cast<float4*>(&w[0]) = *reinterpret_cast<float4*>(&Bs[kk][tx * 4]);
            #pragma unroll
            for (int i = 0; i < 8; i++)
                #pragma unroll
                for (int j = 0; j < 4; j++)
                    acc[i][j] = fmaf(a[i], w[j], acc[i][j]);
        }
        __syncthreads();
    }

    const float inv_scale = 0.35355339059327373f;
    float qb[4];
    #pragma unroll
    for (int j = 0; j < 4; j++) qb[j] = bqkv[h * 64 + tx * 4 + j];

    #pragma unroll
    for (int pass = 0; pass < 2; pass++) {
        __syncthreads();
        #pragma unroll
        for (int i = 0; i < 4; i++) {
            const int ii = pass * 4 + i;
            float q4[4];
            #pragma unroll
            for (int j = 0; j < 4; j++)
                q4[j] = feature_map((acc[ii][j] + qb[j]) * inv_scale);
            *reinterpret_cast<float4*>(&qS[ty * 4 + i][tx * 4]) =
                make_float4(q4[0], q4[1], q4[2], q4[3]);
        }
        __syncthreads();

        float oacc[4][4] = {};
        float z[4] = {};
        #pragma unroll
        for (int d = 0; d < 64; d++) {
            float kv4[4];
            *reinterpret_cast<float4*>(kv4) = *reinterpret_cast<float4*>(&kvS[d][tx * 4]);
            #pragma unroll
            for (int i = 0; i < 4; i++) {
                const float qv = qS[ty * 4 + i][d];
                z[i] += qv;
                #pragma unroll
                for (int j = 0; j < 4; j++)
                    oacc[i][j] = fmaf(qv, kv4[j], oacc[i][j]);
            }
        }
        #pragma unroll
        for (int i = 0; i < 4; i++) {
            const float inv = 1.0f / (z[i] + 1e-6f);
            const int grow = mBase + pass * 64 + ty * 4 + i;
            *reinterpret_cast<float4*>(&attn[(size_t)grow * C_ + h * 64 + tx * 4]) =
                make_float4(oacc[i][0] * inv, oacc[i][1] * inv,
                            oacc[i][2] * inv, oacc[i][3] * inv);
        }
    }
}

// ---------------------------------------------------------------------------
// K3: out-projection SGEMM: out[16384,1024] = attn @ Wout + bout
// ---------------------------------------------------------------------------
__global__ __launch_bounds__(256)
void outproj_kernel(const float* __restrict__ A, const float* __restrict__ W,
                    const float* __restrict__ bias, float* __restrict__ out)
{
    __shared__ float As[16][132];
    __shared__ float Bs[16][128];

    const int tid = threadIdx.x;
    const int tx = tid & 15;
    const int ty = tid >> 4;
    const int mBase = blockIdx.y * 128;
    const int nBase = blockIdx.x * 128;

    float acc[8][8];
    #pragma unroll
    for (int i = 0; i < 8; i++)
        #pragma unroll
        for (int j = 0; j < 8; j++) acc[i][j] = 0.0f;

    for (int k0 = 0; k0 < C_; k0 += 16) {
        #pragma unroll
        for (int l = 0; l < 2; l++) {
            int gid = tid + l * 256;
            int row = gid >> 2, c4 = gid & 3;
            const float4 a4 = *reinterpret_cast<const float4*>(
                &A[(size_t)(mBase + row) * C_ + k0 + c4 * 4]);
            As[c4 * 4 + 0][row] = a4.x;
            As[c4 * 4 + 1][row] = a4.y;
            As[c4 * 4 + 2][row] = a4.z;
            As[c4 * 4 + 3][row] = a4.w;
        }
        #pragma unroll
        for (int l = 0; l < 2; l++) {
            int gid = tid + l * 256;
            int row = gid >> 5, c4 = gid & 31;
            *reinterpret_cast<float4*>(&Bs[row][c4 * 4]) =
                *reinterpret_cast<const float4*>(
                    &W[(size_t)(k0 + row) * C_ + nBase + c4 * 4]);
        }
        __syncthreads();

        #pragma unroll
        for (int kk = 0; kk < 16; kk++) {
            float a[8], w[8];
            *reinterpret_cast<float4*>(&a[0]) = *reinterpret_cast<float4*>(&As[kk][ty * 4]);
            *reinterpret_cast<float4*>(&a[4]) = *reinterpret_cast<float4*>(&As[kk][64 + ty * 4]);
            *reinterpret_cast<float4*>(&w[0]) = *reinterpret_cast<float4*>(&Bs[kk][tx * 4]);
            *reinterpret_cast<float4*>(&w[4]) = *reinterpret_cast<float4*>(&Bs[kk][64 + tx * 4]);
            #pragma unroll
            for (int i = 0; i < 8; i++)
                #pragma unroll
                for (int j = 0; j < 8; j++)
                    acc[i][j] = fmaf(a[i], w[j], acc[i][j]);
        }
        __syncthreads();
    }

    #pragma unroll
    for (int i = 0; i < 8; i++) {
        const int r = mBase + ((i < 4) ? (ty * 4 + i) : (64 + ty * 4 + (i - 4)));
        #pragma unroll
        for (int jg = 0; jg < 2; jg++) {
            const int c0 = nBase + jg * 64 + tx * 4;
            *reinterpret_cast<float4*>(&out[(size_t)r * C_ + c0]) =
                make_float4(acc[i][jg * 4 + 0] + bias[c0 + 0],
                            acc[i][jg * 4 + 1] + bias[c0 + 1],
                            acc[i][jg * 4 + 2] + bias[c0 + 2],
                            acc[i][jg * 4 + 3] + bias[c0 + 3]);
        }
    }
}

// ---------------------------------------------------------------------------
extern "C" void kernel_launch(void* const* d_in, const int* in_sizes, int n_in,
                              void* d_out, int out_size, void* d_ws, size_t ws_size,
                              hipStream_t stream)
{
    const float* x    = (const float*)d_in[0];
    const float* Wqkv = (const float*)d_in[1];
    const float* bqkv = (const float*)d_in[2];
    const float* Wout = (const float*)d_in[3];
    const float* bout = (const float*)d_in[4];
    float* out = (float*)d_out;

    float* ws   = (float*)d_ws;
    float* attn = ws;                           // [BT, C]   67 MB
    float* kv   = ws + (size_t)BT_ * C_;        // [B,H,D,D]  1 MB
    // peak ws use: ~68.2 MB

    hipMemsetAsync(kv, 0, (size_t)B_ * H_ * D_ * D_ * sizeof(float), stream);

    dim3 g1(H_, BT_ / 128);
    kv_fused_kernel<<<g1, 256, 0, stream>>>(x, Wqkv, bqkv, kv);

    dim3 g2(H_, BT_ / 128);
    qattn_kernel<<<g2, 256, 0, stream>>>(x, Wqkv, bqkv, kv, attn);

    dim3 g3(C_ / 128, BT_ / 128);
    outproj_kernel<<<g3, 256, 0, stream>>>(attn, Wout, bout, out);
}

// Round 3
// 509.616 us; speedup vs baseline: 3.4499x; 3.4499x over previous
//
#include <hip/hip_runtime.h>
#include <hip/hip_bf16.h>
#include <math.h>

#define B_ 4
#define T_ 4096
#define H_ 16
#define D_ 64
#define C_ 1024
#define BT_ (B_*T_)

using short8  = __attribute__((ext_vector_type(8))) short;
using floatx4 = __attribute__((ext_vector_type(4))) float;

__device__ __forceinline__ float feature_map(float x) {
    return x > 0.0f ? x + 1.0f : __expf(x);   // elu(x)+1
}
__device__ __forceinline__ unsigned short f2bf(float x) {
    union { __hip_bfloat16 b; unsigned short u; } c;
    c.b = __float2bfloat16(x);                 // RNE
    return c.u;
}
__device__ __forceinline__ float bf2f(unsigned short u) {
    union { unsigned int u; float f; } c;
    c.u = (unsigned)u << 16;                   // exact
    return c.f;
}
// async 16B/lane global->LDS; lds dest = wave-uniform base + lane*16
__device__ __forceinline__ void async16(const void* g, void* l) {
    __builtin_amdgcn_global_load_lds(
        (const __attribute__((address_space(1))) void*)g,
        (__attribute__((address_space(3))) void*)l, 16, 0, 0);
}

// ---------------------------------------------------------------------------
// K0a: x fp32 -> bf16 (row-major [BT][C])
// ---------------------------------------------------------------------------
__global__ __launch_bounds__(256)
void convert_x_kernel(const float4* __restrict__ x, ushort* __restrict__ xb)
{
    const size_t i = (size_t)blockIdx.x * 256 + threadIdx.x;  // BT*C/4 threads
    const float4 v = x[i];
    *reinterpret_cast<ushort4*>(&xb[i * 4]) =
        make_ushort4(f2bf(v.x), f2bf(v.y), f2bf(v.z), f2bf(v.w));
}

// ---------------------------------------------------------------------------
// K0b: W[K][N] fp32 -> WT[N][K] bf16 (32x32 LDS tile transpose)
// ---------------------------------------------------------------------------
__global__ __launch_bounds__(256)
void transpose_bf16_kernel(const float* __restrict__ W, ushort* __restrict__ WT,
                           int K, int N)
{
    __shared__ float t[32][33];
    const int n0 = blockIdx.x * 32, k0 = blockIdx.y * 32;
    const int r = threadIdx.x >> 5, c = threadIdx.x & 31;   // r 0..7, c 0..31
    #pragma unroll
    for (int i = 0; i < 4; i++)
        t[r + 8 * i][c] = W[(size_t)(k0 + r + 8 * i) * N + n0 + c];
    __syncthreads();
    #pragma unroll
    for (int i = 0; i < 4; i++)
        WT[(size_t)(n0 + r + 8 * i) * K + k0 + c] = f2bf(t[c][r + 8 * i]);
}

// ---------------------------------------------------------------------------
// K1: per-head fused [128x1024]x[1024x128(k|v)] bf16-MFMA GEMM
//     + in-LDS feature map + vector k^T v reduction -> atomicAdd kv.
// block = (head, 128-row tile); 256 thr = 4 waves (2x2), wave = 64x64 = 4x4 MFMA tiles.
// ---------------------------------------------------------------------------
__global__ __launch_bounds__(256)
void kv_mfma_kernel(const ushort* __restrict__ xb, const ushort* __restrict__ WqkvT,
                    const float* __restrict__ bqkv, float* __restrict__ kv)
{
    __shared__ __align__(16) unsigned char smem[34816];
    ushort* As = (ushort*)smem;                      // [128][32] bf16
    ushort* Bs = (ushort*)(smem + 8192);             // [128][32] bf16
    float (*kS)[68] = (float (*)[68])smem;           // [64][68] f32 (epilogue)
    float (*vS)[68] = (float (*)[68])(smem + 17408);

    const int tid = threadIdx.x;
    const int w = tid >> 6, l = tid & 63;
    const int wm = w >> 1, wn = w & 1;
    const int lr = l & 15, lk8 = (l >> 4) * 8;
    const int h = blockIdx.x;
    const int mBase = blockIdx.y * 128;
    const int bb = mBase >> 12;

    // staging coords: wave w stages local rows w*32 .. w*32+31 (2 insts of 16 rows)
    const int srow = w * 32 + (l >> 2);
    const int scol = (l & 3) * 8;
    const ushort* gA = xb + (size_t)(mBase + srow) * C_ + scol;
    const int br0 = (srow < 64)      ? (C_ + h * 64 + srow)       : (2 * C_ + h * 64 + srow - 64);
    const int br1 = (srow + 16 < 64) ? (C_ + h * 64 + srow + 16)  : (2 * C_ + h * 64 + srow - 48);
    const ushort* gB0 = WqkvT + (size_t)br0 * C_ + scol;
    const ushort* gB1 = WqkvT + (size_t)br1 * C_ + scol;
    void* ldsA = (void*)(smem + w * 2048);
    void* ldsB = (void*)(smem + 8192 + w * 2048);

    floatx4 acc[4][4];
    #pragma unroll
    for (int i = 0; i < 4; i++)
        #pragma unroll
        for (int j = 0; j < 4; j++) acc[i][j] = (floatx4)0.0f;

    for (int k0 = 0; k0 < C_; k0 += 32) {
        __syncthreads();
        async16(gA + k0, ldsA);
        async16(gA + 16 * C_ + k0, (void*)((char*)ldsA + 1024));
        async16(gB0 + k0, ldsB);
        async16(gB1 + k0, (void*)((char*)ldsB + 1024));
        __syncthreads();

        short8 af[4], bf[4];
        #pragma unroll
        for (int mt = 0; mt < 4; mt++)
            af[mt] = *(const short8*)&As[(wm * 64 + mt * 16 + lr) * 32 + lk8];
        #pragma unroll
        for (int nt = 0; nt < 4; nt++)
            bf[nt] = *(const short8*)&Bs[(wn * 64 + nt * 16 + lr) * 32 + lk8];
        #pragma unroll
        for (int mt = 0; mt < 4; mt++)
            #pragma unroll
            for (int nt = 0; nt < 4; nt++)
                acc[mt][nt] = __builtin_amdgcn_mfma_f32_16x16x32_bf16(
                    af[mt], bf[nt], acc[mt][nt], 0, 0, 0);
    }

    // ---- epilogue: two 64-row passes; k_m,v -> LDS; vector k^T v ----
    const float inv_scale = 0.35355339059327373f;  // 1/64^0.25
    const int bbias = (wn ? 2 * C_ : C_) + h * 64;
    const int ty = tid >> 4, tx = tid & 15;
    float acc2[4][4] = {};

    #pragma unroll
    for (int p = 0; p < 2; p++) {
        __syncthreads();
        if (wm == p) {
            #pragma unroll
            for (int mt = 0; mt < 4; mt++)
                #pragma unroll
                for (int nt = 0; nt < 4; nt++)
                    #pragma unroll
                    for (int i = 0; i < 4; i++) {
                        const int rr = mt * 16 + (l >> 4) * 4 + i;  // 0..63
                        const int cc = nt * 16 + lr;                // 0..63
                        const float val = acc[mt][nt][i] + bqkv[bbias + cc];
                        if (wn == 0) kS[rr][cc] = feature_map(val * inv_scale);
                        else         vS[rr][cc] = val;
                    }
        }
        __syncthreads();
        #pragma unroll 4
        for (int r = 0; r < 64; r++) {
            float k4[4], v4[4];
            *reinterpret_cast<float4*>(k4) = *reinterpret_cast<float4*>(&kS[r][ty * 4]);
            *reinterpret_cast<float4*>(v4) = *reinterpret_cast<float4*>(&vS[r][tx * 4]);
            #pragma unroll
            for (int i = 0; i < 4; i++)
                #pragma unroll
                for (int j = 0; j < 4; j++)
                    acc2[i][j] = fmaf(k4[i], v4[j], acc2[i][j]);
        }
    }

    float* kvb = kv + (size_t)(bb * H_ + h) * (D_ * D_);
    #pragma unroll
    for (int i = 0; i < 4; i++)
        #pragma unroll
        for (int j = 0; j < 4; j++)
            atomicAdd(&kvb[(ty * 4 + i) * D_ + tx * 4 + j], acc2[i][j]);
}

// ---------------------------------------------------------------------------
// K2: head-pair fused q GEMM [128x1024]x[1024x128(q_h0|q_h1)] bf16-MFMA
//     + apply (q_m . kv)/(sum_d q_m + 1e-6) -> attn (bf16).
// ---------------------------------------------------------------------------
__global__ __launch_bounds__(256)
void qattn_mfma_kernel(const ushort* __restrict__ xb, const ushort* __restrict__ WqkvT,
                       const float* __restrict__ bqkv, const float* __restrict__ kv,
                       ushort* __restrict__ attn)
{
    __shared__ __align__(16) unsigned char smem[52224];
    ushort* As = (ushort*)smem;                       // [128][32]
    ushort* Bs = (ushort*)(smem + 8192);              // [128][32]
    float (*qS)[132] = (float (*)[132])smem;          // [64][132] f32 (33792 B)
    ushort* kvsb = (ushort*)(smem + 33792);           // [2][64][72] bf16 (18432 B)

    const int tid = threadIdx.x;
    const int w = tid >> 6, l = tid & 63;
    const int wm = w >> 1, wn = w & 1;
    const int lr = l & 15, lk8 = (l >> 4) * 8;
    const int hp = blockIdx.x;                        // head pair: h0=2hp, h1=2hp+1
    const int mBase = blockIdx.y * 128;
    const int bb = mBase >> 12;

    // load kv for both heads -> bf16 LDS (persistent region)
    {
        const float* kvg = kv + ((size_t)bb * H_ + hp * 2) * (D_ * D_);
        for (int t = tid; t < 8192; t += 256) {
            const int hh = t >> 12, rem = t & 4095, d = rem >> 6, m = rem & 63;
            kvsb[hh * 4608 + d * 72 + m] = f2bf(kvg[t]);
        }
    }

    const int srow = w * 32 + (l >> 2);
    const int scol = (l & 3) * 8;
    const ushort* gA = xb + (size_t)(mBase + srow) * C_ + scol;
    const ushort* gB = WqkvT + (size_t)(hp * 128 + srow) * C_ + scol;
    void* ldsA = (void*)(smem + w * 2048);
    void* ldsB = (void*)(smem + 8192 + w * 2048);

    floatx4 acc[4][4];
    #pragma unroll
    for (int i = 0; i < 4; i++)
        #pragma unroll
        for (int j = 0; j < 4; j++) acc[i][j] = (floatx4)0.0f;

    for (int k0 = 0; k0 < C_; k0 += 32) {
        __syncthreads();
        async16(gA + k0, ldsA);
        async16(gA + 16 * C_ + k0, (void*)((char*)ldsA + 1024));
        async16(gB + k0, ldsB);
        async16(gB + 16 * C_ + k0, (void*)((char*)ldsB + 1024));
        __syncthreads();

        short8 af[4], bfr[4];
        #pragma unroll
        for (int mt = 0; mt < 4; mt++)
            af[mt] = *(const short8*)&As[(wm * 64 + mt * 16 + lr) * 32 + lk8];
        #pragma unroll
        for (int nt = 0; nt < 4; nt++)
            bfr[nt] = *(const short8*)&Bs[(wn * 64 + nt * 16 + lr) * 32 + lk8];
        #pragma unroll
        for (int mt = 0; mt < 4; mt++)
            #pragma unroll
            for (int nt = 0; nt < 4; nt++)
                acc[mt][nt] = __builtin_amdgcn_mfma_f32_16x16x32_bf16(
                    af[mt], bfr[nt], acc[mt][nt], 0, 0, 0);
    }

    const float inv_scale = 0.35355339059327373f;
    const int rq = tid >> 4, tx = tid & 15;

    #pragma unroll
    for (int p = 0; p < 2; p++) {
        __syncthreads();
        if (wm == p) {
            #pragma unroll
            for (int mt = 0; mt < 4; mt++)
                #pragma unroll
                for (int nt = 0; nt < 4; nt++)
                    #pragma unroll
                    for (int i = 0; i < 4; i++) {
                        const int rr = mt * 16 + (l >> 4) * 4 + i;     // 0..63
                        const int cc = wn * 64 + nt * 16 + lr;         // 0..127
                        qS[rr][cc] = feature_map(
                            (acc[mt][nt][i] + bqkv[hp * 128 + cc]) * inv_scale);
                    }
        }
        __syncthreads();

        float o0[4][4] = {}, o1[4][4] = {};
        float z0[4] = {}, z1[4] = {};
        #pragma unroll 2
        for (int d = 0; d < 64; d++) {
            const ushort4 a0 = *(const ushort4*)&kvsb[d * 72 + tx * 4];
            const ushort4 a1 = *(const ushort4*)&kvsb[4608 + d * 72 + tx * 4];
            const float kv0[4] = {bf2f(a0.x), bf2f(a0.y), bf2f(a0.z), bf2f(a0.w)};
            const float kv1[4] = {bf2f(a1.x), bf2f(a1.y), bf2f(a1.z), bf2f(a1.w)};
            #pragma unroll
            for (int i = 0; i < 4; i++) {
                const float q0 = qS[rq * 4 + i][d];
                const float q1 = qS[rq * 4 + i][64 + d];
                z0[i] += q0; z1[i] += q1;
                #pragma unroll
                for (int j = 0; j < 4; j++) {
                    o0[i][j] = fmaf(q0, kv0[j], o0[i][j]);
                    o1[i][j] = fmaf(q1, kv1[j], o1[i][j]);
                }
            }
        }
        #pragma unroll
        for (int i = 0; i < 4; i++) {
            const size_t t = (size_t)(mBase + p * 64 + rq * 4 + i);
            const float i0 = 1.0f / (z0[i] + 1e-6f);
            const float i1 = 1.0f / (z1[i] + 1e-6f);
            *reinterpret_cast<ushort4*>(&attn[t * C_ + hp * 128 + tx * 4]) =
                make_ushort4(f2bf(o0[i][0] * i0), f2bf(o0[i][1] * i0),
                             f2bf(o0[i][2] * i0), f2bf(o0[i][3] * i0));
            *reinterpret_cast<ushort4*>(&attn[t * C_ + hp * 128 + 64 + tx * 4]) =
                make_ushort4(f2bf(o1[i][0] * i1), f2bf(o1[i][1] * i1),
                             f2bf(o1[i][2] * i1), f2bf(o1[i][3] * i1));
        }
    }
}

// ---------------------------------------------------------------------------
// K3: out-proj [16384x1024]x[1024x1024] bf16-MFMA, +bout, fp32 out
// ---------------------------------------------------------------------------
__global__ __launch_bounds__(256)
void outproj_mfma_kernel(const ushort* __restrict__ attn, const ushort* __restrict__ WoutT,
                         const float* __restrict__ bout, float* __restrict__ out)
{
    __shared__ __align__(16) unsigned char smem[16384];
    ushort* As = (ushort*)smem;
    ushort* Bs = (ushort*)(smem + 8192);

    const int tid = threadIdx.x;
    const int w = tid >> 6, l = tid & 63;
    const int wm = w >> 1, wn = w & 1;
    const int lr = l & 15, lk8 = (l >> 4) * 8;
    const int mBase = blockIdx.y * 128;
    const int nBase = blockIdx.x * 128;

    const int srow = w * 32 + (l >> 2);
    const int scol = (l & 3) * 8;
    const ushort* gA = attn + (size_t)(mBase + srow) * C_ + scol;
    const ushort* gB = WoutT + (size_t)(nBase + srow) * C_ + scol;
    void* ldsA = (void*)(smem + w * 2048);
    void* ldsB = (void*)(smem + 8192 + w * 2048);

    floatx4 acc[4][4];
    #pragma unroll
    for (int i = 0; i < 4; i++)
        #pragma unroll
        for (int j = 0; j < 4; j++) acc[i][j] = (floatx4)0.0f;

    for (int k0 = 0; k0 < C_; k0 += 32) {
        __syncthreads();
        async16(gA + k0, ldsA);
        async16(gA + 16 * C_ + k0, (void*)((char*)ldsA + 1024));
        async16(gB + k0, ldsB);
        async16(gB + 16 * C_ + k0, (void*)((char*)ldsB + 1024));
        __syncthreads();

        short8 af[4], bfr[4];
        #pragma unroll
        for (int mt = 0; mt < 4; mt++)
            af[mt] = *(const short8*)&As[(wm * 64 + mt * 16 + lr) * 32 + lk8];
        #pragma unroll
        for (int nt = 0; nt < 4; nt++)
            bfr[nt] = *(const short8*)&Bs[(wn * 64 + nt * 16 + lr) * 32 + lk8];
        #pragma unroll
        for (int mt = 0; mt < 4; mt++)
            #pragma unroll
            for (int nt = 0; nt < 4; nt++)
                acc[mt][nt] = __builtin_amdgcn_mfma_f32_16x16x32_bf16(
                    af[mt], bfr[nt], acc[mt][nt], 0, 0, 0);
    }

    #pragma unroll
    for (int mt = 0; mt < 4; mt++)
        #pragma unroll
        for (int nt = 0; nt < 4; nt++) {
            const int cc = nBase + wn * 64 + nt * 16 + lr;
            const float bv = bout[cc];
            #pragma unroll
            for (int i = 0; i < 4; i++) {
                const int rr = mBase + wm * 64 + mt * 16 + (l >> 4) * 4 + i;
                out[(size_t)rr * C_ + cc] = acc[mt][nt][i] + bv;
            }
        }
}

// ---------------------------------------------------------------------------
extern "C" void kernel_launch(void* const* d_in, const int* in_sizes, int n_in,
                              void* d_out, int out_size, void* d_ws, size_t ws_size,
                              hipStream_t stream)
{
    const float* x    = (const float*)d_in[0];
    const float* Wqkv = (const float*)d_in[1];
    const float* bqkv = (const float*)d_in[2];
    const float* Wout = (const float*)d_in[3];
    const float* bout = (const float*)d_in[4];
    float* out = (float*)d_out;

    char* ws = (char*)d_ws;
    ushort* xb     = (ushort*)ws;                       // 33,554,432 B
    ushort* WqkvT  = (ushort*)(ws + 33554432);          //  6,291,456 B
    ushort* WoutT  = (ushort*)(ws + 39845888);          //  2,097,152 B
    ushort* attn   = (ushort*)(ws + 41943040);          // 33,554,432 B
    float*  kv     = (float*) (ws + 75497472);          //  1,048,576 B  (total 76.5 MB)

    hipMemsetAsync(kv, 0, (size_t)B_ * H_ * D_ * D_ * sizeof(float), stream);

    convert_x_kernel<<<(BT_ * C_ / 4) / 256, 256, 0, stream>>>((const float4*)x, xb);
    transpose_bf16_kernel<<<dim3(3 * C_ / 32, C_ / 32), 256, 0, stream>>>(Wqkv, WqkvT, C_, 3 * C_);
    transpose_bf16_kernel<<<dim3(C_ / 32, C_ / 32), 256, 0, stream>>>(Wout, WoutT, C_, C_);

    kv_mfma_kernel<<<dim3(H_, BT_ / 128), 256, 0, stream>>>(xb, WqkvT, bqkv, kv);
    qattn_mfma_kernel<<<dim3(H_ / 2, BT_ / 128), 256, 0, stream>>>(xb, WqkvT, bqkv, kv, attn);
    outproj_mfma_kernel<<<dim3(C_ / 128, BT_ / 128), 256, 0, stream>>>(attn, WoutT, bout, out);
}

// Round 4
// 350.644 us; speedup vs baseline: 5.0140x; 1.4534x over previous
//
#include <hip/hip_runtime.h>
#include <hip/hip_bf16.h>
#include <math.h>

#define B_ 4
#define T_ 4096
#define H_ 16
#define D_ 64
#define C_ 1024
#define BT_ (B_*T_)

using short8  = __attribute__((ext_vector_type(8))) short;
using floatx4 = __attribute__((ext_vector_type(4))) float;

__device__ __forceinline__ float feature_map(float x) {
    return x > 0.0f ? x + 1.0f : __expf(x);   // elu(x)+1
}
__device__ __forceinline__ unsigned short f2bf(float x) {
    union { __hip_bfloat16 b; unsigned short u; } c;
    c.b = __float2bfloat16(x);                 // RNE
    return c.u;
}
__device__ __forceinline__ float bf2f(unsigned short u) {
    union { unsigned int u; float f; } c;
    c.u = (unsigned)u << 16;                   // exact
    return c.f;
}
__device__ __forceinline__ void async16(const void* g, void* l) {
    __builtin_amdgcn_global_load_lds(
        (const __attribute__((address_space(1))) void*)g,
        (__attribute__((address_space(3))) void*)l, 16, 0, 0);
}

// ---------------------------------------------------------------------------
// K0a: x fp32 -> bf16
// ---------------------------------------------------------------------------
__global__ __launch_bounds__(256)
void convert_x_kernel(const float4* __restrict__ x, ushort* __restrict__ xb)
{
    const size_t i = (size_t)blockIdx.x * 256 + threadIdx.x;
    const float4 v = x[i];
    *reinterpret_cast<ushort4*>(&xb[i * 4]) =
        make_ushort4(f2bf(v.x), f2bf(v.y), f2bf(v.z), f2bf(v.w));
}

// ---------------------------------------------------------------------------
// K0b: W[K][N] fp32 -> WT[N][K] bf16
// ---------------------------------------------------------------------------
__global__ __launch_bounds__(256)
void transpose_bf16_kernel(const float* __restrict__ W, ushort* __restrict__ WT,
                           int K, int N)
{
    __shared__ float t[32][33];
    const int n0 = blockIdx.x * 32, k0 = blockIdx.y * 32;
    const int r = threadIdx.x >> 5, c = threadIdx.x & 31;
    #pragma unroll
    for (int i = 0; i < 4; i++)
        t[r + 8 * i][c] = W[(size_t)(k0 + r + 8 * i) * N + n0 + c];
    __syncthreads();
    #pragma unroll
    for (int i = 0; i < 4; i++)
        WT[(size_t)(n0 + r + 8 * i) * K + k0 + c] = f2bf(t[c][r + 8 * i]);
}

// ---------------------------------------------------------------------------
// K1: per-head [128x1024]x[1024x128(k|v)] bf16-MFMA GEMM, epilogue:
//     k_m,v -> LDS transposed bf16 -> k^T v via MFMA (16/wave) -> atomicAdd.
// ---------------------------------------------------------------------------
__global__ __launch_bounds__(256)
void kv_mfma_kernel(const ushort* __restrict__ xb, const ushort* __restrict__ WqkvT,
                    const float* __restrict__ bqkv, float* __restrict__ kv)
{
    __shared__ __align__(16) unsigned char smem[34816];
    ushort* As = (ushort*)smem;                  // [128][32] bf16 (main loop)
    ushort* Bs = (ushort*)(smem + 8192);         // [128][32] bf16
    ushort* kT = (ushort*)smem;                  // [64][136] bf16 (epilogue) = k_m^T
    ushort* vT = kT + 64 * 136;                  // [64][136] bf16            = v^T

    const int tid = threadIdx.x;
    const int w = tid >> 6, l = tid & 63;
    const int wm = w >> 1, wn = w & 1;
    const int lr = l & 15, quad = l >> 4;
    const int lk8 = quad * 8;
    const int h = blockIdx.x;
    const int mBase = blockIdx.y * 128;
    const int bb = mBase >> 12;

    const int srow = w * 32 + (l >> 2);
    const int scol = (l & 3) * 8;
    const ushort* gA = xb + (size_t)(mBase + srow) * C_ + scol;
    const int br0 = (srow < 64)      ? (C_ + h * 64 + srow)      : (2 * C_ + h * 64 + srow - 64);
    const int br1 = (srow + 16 < 64) ? (C_ + h * 64 + srow + 16) : (2 * C_ + h * 64 + srow - 48);
    const ushort* gB0 = WqkvT + (size_t)br0 * C_ + scol;
    const ushort* gB1 = WqkvT + (size_t)br1 * C_ + scol;
    void* ldsA = (void*)(smem + w * 2048);
    void* ldsB = (void*)(smem + 8192 + w * 2048);

    floatx4 acc[4][4];
    #pragma unroll
    for (int i = 0; i < 4; i++)
        #pragma unroll
        for (int j = 0; j < 4; j++) acc[i][j] = (floatx4)0.0f;

    for (int k0 = 0; k0 < C_; k0 += 32) {
        __syncthreads();
        async16(gA + k0, ldsA);
        async16(gA + 16 * C_ + k0, (void*)((char*)ldsA + 1024));
        async16(gB0 + k0, ldsB);
        async16(gB1 + k0, (void*)((char*)ldsB + 1024));
        __syncthreads();

        short8 af[4], bf[4];
        #pragma unroll
        for (int mt = 0; mt < 4; mt++)
            af[mt] = *(const short8*)&As[(wm * 64 + mt * 16 + lr) * 32 + lk8];
        #pragma unroll
        for (int nt = 0; nt < 4; nt++)
            bf[nt] = *(const short8*)&Bs[(wn * 64 + nt * 16 + lr) * 32 + lk8];
        #pragma unroll
        for (int mt = 0; mt < 4; mt++)
            #pragma unroll
            for (int nt = 0; nt < 4; nt++)
                acc[mt][nt] = __builtin_amdgcn_mfma_f32_16x16x32_bf16(
                    af[mt], bf[nt], acc[mt][nt], 0, 0, 0);
    }

    // ---- epilogue: transpose-store k_m (bf16) and v (bf16), then MFMA k^T v
    const float inv_scale = 0.35355339059327373f;  // 1/64^0.25
    const int bbias = (wn ? 2 * C_ : C_) + h * 64;

    __syncthreads();                               // As/Bs reads drained
    {
        ushort* dst = wn ? vT : kT;
        #pragma unroll
        for (int nt = 0; nt < 4; nt++) {
            const int cc = nt * 16 + lr;           // d (k) or m (v), 0..63
            const float bv = bqkv[bbias + cc];
            #pragma unroll
            for (int mt = 0; mt < 4; mt++) {
                float v0 = acc[mt][nt][0] + bv, v1 = acc[mt][nt][1] + bv;
                float v2 = acc[mt][nt][2] + bv, v3 = acc[mt][nt][3] + bv;
                if (wn == 0) {
                    v0 = feature_map(v0 * inv_scale); v1 = feature_map(v1 * inv_scale);
                    v2 = feature_map(v2 * inv_scale); v3 = feature_map(v3 * inv_scale);
                }
                // t = wm*64 + mt*16 + quad*4 + i  (4 consecutive -> ushort4)
                *(ushort4*)&dst[cc * 136 + wm * 64 + mt * 16 + quad * 4] =
                    make_ushort4(f2bf(v0), f2bf(v1), f2bf(v2), f2bf(v3));
            }
        }
    }
    __syncthreads();

    // kv[d][m] += sum_t kT[d][t] * vT[m][t] ; wave quadrant 32x32, K=128
    floatx4 acc2[2][2];
    #pragma unroll
    for (int i = 0; i < 2; i++)
        #pragma unroll
        for (int j = 0; j < 2; j++) acc2[i][j] = (floatx4)0.0f;

    #pragma unroll
    for (int kst = 0; kst < 4; kst++) {
        short8 afr[2], bfr[2];
        #pragma unroll
        for (int i = 0; i < 2; i++)
            afr[i] = *(const short8*)&kT[(wm * 32 + i * 16 + lr) * 136 + kst * 32 + lk8];
        #pragma unroll
        for (int j = 0; j < 2; j++)
            bfr[j] = *(const short8*)&vT[(wn * 32 + j * 16 + lr) * 136 + kst * 32 + lk8];
        #pragma unroll
        for (int i = 0; i < 2; i++)
            #pragma unroll
            for (int j = 0; j < 2; j++)
                acc2[i][j] = __builtin_amdgcn_mfma_f32_16x16x32_bf16(
                    afr[i], bfr[j], acc2[i][j], 0, 0, 0);
    }

    float* kvb = kv + (size_t)(bb * H_ + h) * (D_ * D_);
    #pragma unroll
    for (int i = 0; i < 2; i++)
        #pragma unroll
        for (int j = 0; j < 2; j++)
            #pragma unroll
            for (int r = 0; r < 4; r++) {
                const int d = wm * 32 + i * 16 + quad * 4 + r;
                const int m = wn * 32 + j * 16 + lr;
                atomicAdd(&kvb[d * 64 + m], acc2[i][j][r]);
            }
}

// ---------------------------------------------------------------------------
// K2: head-pair q GEMM [128x1024]x[1024x128] bf16-MFMA, epilogue:
//     qS bf16 [t][d] -> z row-sums -> PV via MFMA -> divide -> staged store.
// ---------------------------------------------------------------------------
__global__ __launch_bounds__(256)
void qattn_mfma_kernel(const ushort* __restrict__ xb, const ushort* __restrict__ WqkvT,
                       const float* __restrict__ bqkv, const float* __restrict__ kv,
                       ushort* __restrict__ attn)
{
    __shared__ __align__(16) unsigned char smem[54272];
    ushort* As  = (ushort*)smem;                  // [128][32] (main loop)
    ushort* Bs  = (ushort*)(smem + 8192);         // [128][32]
    ushort* qS  = (ushort*)smem;                  // [128][136] bf16 (epilogue; reused as oS)
    ushort* kvT = (ushort*)(smem + 34816);        // [2][64][72] bf16 (kv transposed)
    float*  zS  = (float*)(smem + 53248);         // [2][128]

    const int tid = threadIdx.x;
    const int w = tid >> 6, l = tid & 63;
    const int wm = w >> 1, wn = w & 1;
    const int lr = l & 15, quad = l >> 4;
    const int lk8 = quad * 8;
    const int hp = blockIdx.x;                    // heads 2hp, 2hp+1
    const int mBase = blockIdx.y * 128;
    const int bb = mBase >> 12;

    // kv[b, 2hp+h][d][m] fp32 -> kvT[h][m][d] bf16 (coalesced read, 2-way LDS write)
    {
        const float* kvg = kv + ((size_t)bb * H_ + hp * 2) * (D_ * D_);
        #pragma unroll
        for (int e = 0; e < 32; e++) {
            const int flat = e * 256 + tid;       // 0..8191
            const int hh = flat >> 12, d = (flat >> 6) & 63, m = flat & 63;
            kvT[hh * 4608 + m * 72 + d] = f2bf(kvg[flat]);
        }
    }

    const int srow = w * 32 + (l >> 2);
    const int scol = (l & 3) * 8;
    const ushort* gA = xb + (size_t)(mBase + srow) * C_ + scol;
    const ushort* gB = WqkvT + (size_t)(hp * 128 + srow) * C_ + scol;
    void* ldsA = (void*)(smem + w * 2048);
    void* ldsB = (void*)(smem + 8192 + w * 2048);

    floatx4 acc[4][4];
    #pragma unroll
    for (int i = 0; i < 4; i++)
        #pragma unroll
        for (int j = 0; j < 4; j++) acc[i][j] = (floatx4)0.0f;

    for (int k0 = 0; k0 < C_; k0 += 32) {
        __syncthreads();
        async16(gA + k0, ldsA);
        async16(gA + 16 * C_ + k0, (void*)((char*)ldsA + 1024));
        async16(gB + k0, ldsB);
        async16(gB + 16 * C_ + k0, (void*)((char*)ldsB + 1024));
        __syncthreads();

        short8 af[4], bfr[4];
        #pragma unroll
        for (int mt = 0; mt < 4; mt++)
            af[mt] = *(const short8*)&As[(wm * 64 + mt * 16 + lr) * 32 + lk8];
        #pragma unroll
        for (int nt = 0; nt < 4; nt++)
            bfr[nt] = *(const short8*)&Bs[(wn * 64 + nt * 16 + lr) * 32 + lk8];
        #pragma unroll
        for (int mt = 0; mt < 4; mt++)
            #pragma unroll
            for (int nt = 0; nt < 4; nt++)
                acc[mt][nt] = __builtin_amdgcn_mfma_f32_16x16x32_bf16(
                    af[mt], bfr[nt], acc[mt][nt], 0, 0, 0);
    }

    const float inv_scale = 0.35355339059327373f;

    __syncthreads();                               // As/Bs reads drained
    // q_m -> qS[t][cc] bf16 (cc = wn*64 + nt*16 + lr spans both heads)
    #pragma unroll
    for (int nt = 0; nt < 4; nt++) {
        const int cc = wn * 64 + nt * 16 + lr;
        const float bv = bqkv[hp * 128 + cc];
        #pragma unroll
        for (int mt = 0; mt < 4; mt++)
            #pragma unroll
            for (int i = 0; i < 4; i++) {
                const int t = wm * 64 + mt * 16 + quad * 4 + i;
                qS[t * 136 + cc] = f2bf(feature_map((acc[mt][nt][i] + bv) * inv_scale));
            }
    }
    __syncthreads();

    // z[h][t] = sum_d qS[t][h*64+d]   (one (t,h) per thread)
    {
        const int t = tid & 127, hh = tid >> 7;
        float s = 0.0f;
        #pragma unroll
        for (int c8 = 0; c8 < 8; c8++) {
            const short8 v = *(const short8*)&qS[t * 136 + hh * 64 + c8 * 8];
            #pragma unroll
            for (int j = 0; j < 8; j++) s += bf2f((unsigned short)v[j]);
        }
        zS[hh * 128 + t] = s;
    }

    // PV: out_h[t][m] = sum_d qS[t][h*64+d] * kvT[h][m][d]; wave: h=wn, t-half=wm
    floatx4 acc3[4][4];
    #pragma unroll
    for (int i = 0; i < 4; i++)
        #pragma unroll
        for (int j = 0; j < 4; j++) acc3[i][j] = (floatx4)0.0f;

    #pragma unroll
    for (int kst = 0; kst < 2; kst++) {
        short8 afr[4], bfr[4];
        #pragma unroll
        for (int mt = 0; mt < 4; mt++)
            afr[mt] = *(const short8*)&qS[(wm * 64 + mt * 16 + lr) * 136 + wn * 64 + kst * 32 + lk8];
        #pragma unroll
        for (int nt = 0; nt < 4; nt++)
            bfr[nt] = *(const short8*)&kvT[wn * 4608 + (nt * 16 + lr) * 72 + kst * 32 + lk8];
        #pragma unroll
        for (int mt = 0; mt < 4; mt++)
            #pragma unroll
            for (int nt = 0; nt < 4; nt++)
                acc3[mt][nt] = __builtin_amdgcn_mfma_f32_16x16x32_bf16(
                    afr[mt], bfr[nt], acc3[mt][nt], 0, 0, 0);
    }
    __syncthreads();                               // zS visible; qS reads drained

    // divide by z, stage bf16 result into qS region (oS[t][h*64+m])
    #pragma unroll
    for (int mt = 0; mt < 4; mt++)
        #pragma unroll
        for (int i = 0; i < 4; i++) {
            const int t = wm * 64 + mt * 16 + quad * 4 + i;
            const float inv = 1.0f / (zS[wn * 128 + t] + 1e-6f);
            #pragma unroll
            for (int nt = 0; nt < 4; nt++)
                qS[t * 136 + wn * 64 + nt * 16 + lr] = f2bf(acc3[mt][nt][i] * inv);
        }
    __syncthreads();

    // coalesced copy-out: 128 rows x 128 ushorts
    #pragma unroll
    for (int it = 0; it < 16; it++) {
        const int flat = it * 256 + tid;          // 0..4095
        const int row = flat >> 5, c = flat & 31;
        *(ushort4*)&attn[(size_t)(mBase + row) * C_ + hp * 128 + c * 4] =
            *(const ushort4*)&qS[row * 136 + c * 4];
    }
}

// ---------------------------------------------------------------------------
// K3: out-proj [16384x1024]x[1024x1024] bf16-MFMA, +bout, fp32 out
// ---------------------------------------------------------------------------
__global__ __launch_bounds__(256)
void outproj_mfma_kernel(const ushort* __restrict__ attn, const ushort* __restrict__ WoutT,
                         const float* __restrict__ bout, float* __restrict__ out)
{
    __shared__ __align__(16) unsigned char smem[16384];
    ushort* As = (ushort*)smem;
    ushort* Bs = (ushort*)(smem + 8192);

    const int tid = threadIdx.x;
    const int w = tid >> 6, l = tid & 63;
    const int wm = w >> 1, wn = w & 1;
    const int lr = l & 15, lk8 = (l >> 4) * 8;
    const int mBase = blockIdx.y * 128;
    const int nBase = blockIdx.x * 128;

    const int srow = w * 32 + (l >> 2);
    const int scol = (l & 3) * 8;
    const ushort* gA = attn + (size_t)(mBase + srow) * C_ + scol;
    const ushort* gB = WoutT + (size_t)(nBase + srow) * C_ + scol;
    void* ldsA = (void*)(smem + w * 2048);
    void* ldsB = (void*)(smem + 8192 + w * 2048);

    floatx4 acc[4][4];
    #pragma unroll
    for (int i = 0; i < 4; i++)
        #pragma unroll
        for (int j = 0; j < 4; j++) acc[i][j] = (floatx4)0.0f;

    for (int k0 = 0; k0 < C_; k0 += 32) {
        __syncthreads();
        async16(gA + k0, ldsA);
        async16(gA + 16 * C_ + k0, (void*)((char*)ldsA + 1024));
        async16(gB + k0, ldsB);
        async16(gB + 16 * C_ + k0, (void*)((char*)ldsB + 1024));
        __syncthreads();

        short8 af[4], bfr[4];
        #pragma unroll
        for (int mt = 0; mt < 4; mt++)
            af[mt] = *(const short8*)&As[(wm * 64 + mt * 16 + lr) * 32 + lk8];
        #pragma unroll
        for (int nt = 0; nt < 4; nt++)
            bfr[nt] = *(const short8*)&Bs[(wn * 64 + nt * 16 + lr) * 32 + lk8];
        #pragma unroll
        for (int mt = 0; mt < 4; mt++)
            #pragma unroll
            for (int nt = 0; nt < 4; nt++)
                acc[mt][nt] = __builtin_amdgcn_mfma_f32_16x16x32_bf16(
                    af[mt], bfr[nt], acc[mt][nt], 0, 0, 0);
    }

    #pragma unroll
    for (int mt = 0; mt < 4; mt++)
        #pragma unroll
        for (int nt = 0; nt < 4; nt++) {
            const int cc = nBase + wn * 64 + nt * 16 + lr;
            const float bv = bout[cc];
            #pragma unroll
            for (int i = 0; i < 4; i++) {
                const int rr = mBase + wm * 64 + mt * 16 + (l >> 4) * 4 + i;
                out[(size_t)rr * C_ + cc] = acc[mt][nt][i] + bv;
            }
        }
}

// ---------------------------------------------------------------------------
extern "C" void kernel_launch(void* const* d_in, const int* in_sizes, int n_in,
                              void* d_out, int out_size, void* d_ws, size_t ws_size,
                              hipStream_t stream)
{
    const float* x    = (const float*)d_in[0];
    const float* Wqkv = (const float*)d_in[1];
    const float* bqkv = (const float*)d_in[2];
    const float* Wout = (const float*)d_in[3];
    const float* bout = (const float*)d_in[4];
    float* out = (float*)d_out;

    char* ws = (char*)d_ws;
    ushort* xb     = (ushort*)ws;                       // 33,554,432 B
    ushort* WqkvT  = (ushort*)(ws + 33554432);          //  6,291,456 B
    ushort* WoutT  = (ushort*)(ws + 39845888);          //  2,097,152 B
    ushort* attn   = (ushort*)(ws + 41943040);          // 33,554,432 B
    float*  kv     = (float*) (ws + 75497472);          //  1,048,576 B

    hipMemsetAsync(kv, 0, (size_t)B_ * H_ * D_ * D_ * sizeof(float), stream);

    convert_x_kernel<<<(BT_ * C_ / 4) / 256, 256, 0, stream>>>((const float4*)x, xb);
    transpose_bf16_kernel<<<dim3(3 * C_ / 32, C_ / 32), 256, 0, stream>>>(Wqkv, WqkvT, C_, 3 * C_);
    transpose_bf16_kernel<<<dim3(C_ / 32, C_ / 32), 256, 0, stream>>>(Wout, WoutT, C_, C_);

    kv_mfma_kernel<<<dim3(H_, BT_ / 128), 256, 0, stream>>>(xb, WqkvT, bqkv, kv);
    qattn_mfma_kernel<<<dim3(H_ / 2, BT_ / 128), 256, 0, stream>>>(xb, WqkvT, bqkv, kv, attn);
    outproj_mfma_kernel<<<dim3(C_ / 128, BT_ / 128), 256, 0, stream>>>(attn, WoutT, bout, out);
}